// Round 9
// baseline (44.227 us; speedup 1.0000x reference)
//
#include <hip/hip_runtime.h>
#include <math.h>

// Problem constants (from setup_inputs)
#define BB 8
#define HW 4096
#define LTXT 8192
#define GG 4096
#define DD 256
#define NBLK 560

// Fused grid: 560 blocks x 256 threads, thread = one input row (64 quats)
//   [0,128)    vision chains:  b = id/16,        chunk = id%16
//   [128,384)  text chains:    b = (id-128)/32,  chunk = %32
//   [384,512)  genomic chains: b = (id-384)/16,  chunk = %16
//   [512,528)  vision audit (16 blocks, thread = row)
//   [528,560)  text audit (32 blocks, thread = position)
// Last-finishing block (device-scope atomic counter) runs finalize inline.
//
// d_ws layout: int counter @byte 0 (zeroed each call via hipMemsetAsync)
//   floats @byte 256: [0,512) vision chunk products, [512,1536) text, [1536,2048) genomic
//   doubles @byte 65536: [0,16) vision-audit partials, [16,48) text-audit partials

struct QF { float w, x, y, z; };

__device__ __forceinline__ QF qmulf(const QF a, const QF b) {
    QF r;
    r.w = fmaf(a.w, b.w, -fmaf(a.x, b.x, fmaf(a.y, b.y, a.z * b.z)));
    r.x = fmaf(a.w, b.x, fmaf(a.x, b.w, fmaf(a.y, b.z, -(a.z * b.y))));
    r.y = fmaf(a.w, b.y, fmaf(a.y, b.w, fmaf(a.z, b.x, -(a.x * b.z))));
    r.z = fmaf(a.w, b.z, fmaf(a.x, b.y, fmaf(a.z, b.w, -(a.y * b.x))));
    return r;
}

// Ordered (non-commutative) 64-lane butterfly: lower lane's product on the left.
__device__ __forceinline__ QF wave_ordered_prod(QF p, int lane) {
    #pragma unroll
    for (int s = 1; s < 64; s <<= 1) {
        QF o;
        o.w = __shfl_xor(p.w, s, 64);
        o.x = __shfl_xor(p.x, s, 64);
        o.y = __shfl_xor(p.y, s, 64);
        o.z = __shfl_xor(p.z, s, 64);
        const bool hi = (lane & s) != 0;
        QF a = hi ? o : p;
        QF b = hi ? p : o;
        p = qmulf(a, b);
    }
    return p;
}

// Thread = one row. Software-pipelined double-buffered weight staging (R5 form).
// Deferred normalization: raw product + s = prod(n_f32 + 1e-8f), one divide/batch.
template<int K, int BQ>
__device__ __forceinline__ void chain_block(
    const float* __restrict__ X, const float* __restrict__ W,
    const float* __restrict__ bias, int rowBase,
    float* __restrict__ out4, float* sprod)
{
    constexpr int V = K + 1;
    constexpr int NB = 64 / BQ;
    const int t = threadIdx.x;
    const int r = rowBase + t;
    float xv[K];
    #pragma unroll
    for (int k = 0; k < K; ++k) xv[k] = X[(size_t)r * K + k];

    float4 A[BQ * V], Bb[BQ * V];
    QF p = {1.0f, 0.0f, 0.0f, 0.0f};

    auto LOADB = [&](float4* dst, int bidx) {
        const float* bb = bias + 4 * (bidx * BQ);
        const float* wb = W + 4 * (bidx * BQ);
        #pragma unroll
        for (int j = 0; j < BQ; ++j) {
            dst[j * V + 0] = *(const float4*)(bb + 4 * j);
            #pragma unroll
            for (int k = 0; k < K; ++k)
                dst[j * V + 1 + k] = *(const float4*)(wb + k * DD + 4 * j);
        }
    };

    auto COMPUTE = [&](const float4* src, int bidx) {
        QF pb; float sb;
        #pragma unroll
        for (int j = 0; j < BQ; ++j) {
            const float4 b4 = src[j * V + 0];
            float l0 = b4.x, l1 = b4.y, l2 = b4.z, l3 = b4.w;
            #pragma unroll
            for (int k = 0; k < K; ++k) {
                const float4 w4 = src[j * V + 1 + k];
                l0 = fmaf(xv[k], w4.x, l0);
                l1 = fmaf(xv[k], w4.y, l1);
                l2 = fmaf(xv[k], w4.z, l2);
                l3 = fmaf(xv[k], w4.w, l3);
            }
            const float n = sqrtf(fmaf(l0, l0, fmaf(l1, l1, fmaf(l2, l2, l3 * l3))));
            QF q = { l0, l1, l2, l3 };
            if (j == 0) { pb = q; sb = n + 1e-8f; }
            else        { pb = qmulf(pb, q); sb *= (n + 1e-8f); }
        }
        const float inv = 1.0f / sb;
        QF pbn = { pb.w * inv, pb.x * inv, pb.y * inv, pb.z * inv };
        if (bidx == 0) p = pbn;
        else           p = qmulf(p, pbn);
    };

    LOADB(A, 0);
    for (int gg = 0; gg < NB / 2; ++gg) {
        LOADB(Bb, 2 * gg + 1);
        COMPUTE(A, 2 * gg);
        const int nb = (2 * gg + 2 < NB) ? (2 * gg + 2) : (NB - 1);
        LOADB(A, nb);
        COMPUTE(Bb, 2 * gg + 1);
    }

    const int lane = t & 63;
    p = wave_ordered_prod(p, lane);

    const int w = t >> 6;
    if (lane == 0) { sprod[w*4+0] = p.w; sprod[w*4+1] = p.x; sprod[w*4+2] = p.y; sprod[w*4+3] = p.z; }
    __syncthreads();
    if (t == 0) {
        QF pp = { sprod[0], sprod[1], sprod[2], sprod[3] };
        #pragma unroll
        for (int wv = 1; wv < 4; ++wv) {
            QF o = { sprod[wv*4+0], sprod[wv*4+1], sprod[wv*4+2], sprod[wv*4+3] };
            pp = qmulf(pp, o);
        }
        float4 outv = { pp.w, pp.x, pp.y, pp.z };
        *(float4*)out4 = outv;
    }
}

__global__ __launch_bounds__(256) void fused_kernel(
    const float* __restrict__ vis, const float* __restrict__ txt, const float* __restrict__ gen,
    const float* __restrict__ Wv, const float* __restrict__ bv,
    const float* __restrict__ Wt, const float* __restrict__ bt,
    const float* __restrict__ Wg, const float* __restrict__ bg,
    int* __restrict__ counter, float* __restrict__ wsf, double* __restrict__ dws,
    float* __restrict__ out)
{
    __shared__ double sred[256];
    __shared__ double sphi[24];
    __shared__ double s_sums[3];     // sumv, sumt, sumw
    __shared__ int s_last;
    float* sprod = (float*)sred;

    const int t  = threadIdx.x;
    const int id = blockIdx.x;

    if (id < 128) {
        const int b = id >> 4, chunk = id & 15;
        chain_block<3, 4>(vis + (size_t)b * HW * 3, Wv, bv, chunk * 256,
                          wsf + (size_t)id * 4, sprod);
    } else if (id < 384) {
        const int i2 = id - 128;
        const int b = i2 >> 5, chunk = i2 & 31;
        chain_block<1, 8>(txt + (size_t)b * LTXT, Wt, bt, chunk * 256,
                          wsf + 512 + (size_t)i2 * 4, sprod);
    } else if (id < 512) {
        const int i2 = id - 384;
        const int b = i2 >> 4, chunk = i2 & 15;
        chain_block<4, 2>(gen + (size_t)b * GG * 4, Wg, bg, chunk * 256,
                          wsf + 1536 + (size_t)i2 * 4, sprod);
    } else if (id < 528) {
        // ---------------- vision audit: thread = row ----------------
        const int aid = id - 512;
        const int r = aid * 256 + t;          // 0..4095
        float gx[8], gy[8], gz[8];
        {
            float vx[8], vy[8], vz[8];
            #pragma unroll
            for (int b = 0; b < 8; ++b) {
                const size_t base = ((size_t)b * HW + r) * 3;
                vx[b] = vis[base]; vy[b] = vis[base+1]; vz[b] = vis[base+2];
            }
            #pragma unroll
            for (int b = 0; b < 8; ++b) {
                if (b == 0)      { gx[b] = vx[1]-vx[0];  gy[b] = vy[1]-vy[0];  gz[b] = vz[1]-vz[0]; }
                else if (b == 7) { gx[b] = vx[7]-vx[6];  gy[b] = vy[7]-vy[6];  gz[b] = vz[7]-vz[6]; }
                else             { gx[b] = (vx[b+1]-vx[b-1])*0.5f; gy[b] = (vy[b+1]-vy[b-1])*0.5f; gz[b] = (vz[b+1]-vz[b-1])*0.5f; }
            }
        }
        double acc = 0.0;
        #pragma unroll 4
        for (int i = 0; i < 64; ++i) {
            const float4 a0 = *(const float4*)(Wv + 4*i);
            const float4 a1 = *(const float4*)(Wv + DD + 4*i);
            const float4 a2 = *(const float4*)(Wv + 2*DD + 4*i);
            const float wq0 = a0.x + a0.y + a0.z + a0.w;
            const float wq1 = a1.x + a1.y + a1.z + a1.w;
            const float wq2 = a2.x + a2.y + a2.z + a2.w;
            float acc8 = 0.0f;
            #pragma unroll
            for (int b = 0; b < 8; ++b)
                acc8 += fabsf(fmaf(gx[b], wq0, fmaf(gy[b], wq1, gz[b] * wq2)));
            acc += (double)acc8;
        }
        sred[t] = acc;
        __syncthreads();
        for (int off = 128; off > 0; off >>= 1) {
            if (t < off) sred[t] += sred[t + off];
            __syncthreads();
        }
        if (t == 0) dws[aid] = sred[0];
    } else {
        // ---------------- text audit (gradient factor) ----------------
        const int aid = id - 528;
        const int l = aid * 256 + t;          // 0..8191
        float tv[8];
        #pragma unroll
        for (int b = 0; b < 8; ++b) tv[b] = txt[(size_t)b * LTXT + l];
        double acc = 0.0;
        #pragma unroll
        for (int b = 0; b < 8; ++b) {
            float gb;
            if (b == 0)      gb = tv[1] - tv[0];
            else if (b == 7) gb = tv[7] - tv[6];
            else             gb = (tv[b+1] - tv[b-1]) * 0.5f;
            acc += (double)fabsf(gb);
        }
        sred[t] = acc;
        __syncthreads();
        for (int off = 128; off > 0; off >>= 1) {
            if (t < off) sred[t] += sred[t + off];
            __syncthreads();
        }
        if (t == 0) dws[16 + aid] = sred[0];
    }

    // -------- completion: last-finishing block runs finalize inline --------
    __syncthreads();
    if (t == 0) {
        __threadfence();                       // release our global writes
        const int old = atomicAdd(counter, 1); // device-scope
        s_last = (old == NBLK - 1) ? 1 : 0;
    }
    __syncthreads();
    if (!s_last) return;
    __threadfence();                           // acquire all blocks' writes

    const int lane = t & 63, w = t >> 6;

    #pragma unroll
    for (int j = 0; j < 6; ++j) {
        const int pair = w * 6 + j;            // 0..23
        const int m = pair >> 3, b = pair & 7;
        const int nch = (m == 1) ? 32 : 16;
        const float* base = wsf + ((m == 0) ? 0 : (m == 1) ? 512 : 1536) + (size_t)b * nch * 4;
        QF p = { 1.0f, 0.0f, 0.0f, 0.0f };
        if (lane < nch) {
            const float4 c0 = *(const float4*)(base + lane * 4);
            p = { c0.x, c0.y, c0.z, c0.w };
        }
        p = wave_ordered_prod(p, lane);
        if (lane == 0) {
            float lat[4];
            if (m == 0) {
                const float x0 = vis[(size_t)b*HW*3], x1 = vis[(size_t)b*HW*3+1], x2 = vis[(size_t)b*HW*3+2];
                #pragma unroll
                for (int c = 0; c < 4; ++c)
                    lat[c] = fmaf(x0, Wv[c], fmaf(x1, Wv[DD+c], fmaf(x2, Wv[2*DD+c], bv[c])));
            } else if (m == 1) {
                const float x0 = txt[(size_t)b*LTXT];
                #pragma unroll
                for (int c = 0; c < 4; ++c) lat[c] = fmaf(x0, Wt[c], bt[c]);
            } else {
                const float x0 = gen[(size_t)b*GG*4], x1 = gen[(size_t)b*GG*4+1],
                            x2 = gen[(size_t)b*GG*4+2], x3 = gen[(size_t)b*GG*4+3];
                #pragma unroll
                for (int c = 0; c < 4; ++c)
                    lat[c] = fmaf(x0, Wg[c], fmaf(x1, Wg[DD+c], fmaf(x2, Wg[2*DD+c], fmaf(x3, Wg[3*DD+c], bg[c]))));
            }
            const float n = sqrtf(fmaf(lat[0], lat[0], fmaf(lat[1], lat[1], fmaf(lat[2], lat[2], lat[3] * lat[3]))));
            const float inv = 1.0f / (n + 1e-8f);
            QF q0 = { lat[0]*inv, lat[1]*inv, lat[2]*inv, lat[3]*inv };
            p = qmulf(p, q0);
            double ww = (double)p.w;
            if (ww > 1.0) ww = 1.0;
            if (ww < -1.0) ww = -1.0;
            sphi[pair] = 2.0 * acos(ww);
        }
    }
    __syncthreads();

    // vision audit sum (16 partials)
    sred[t] = (t < 16) ? dws[t] : 0.0; __syncthreads();
    for (int off = 128; off > 0; off >>= 1) { if (t < off) sred[t] += sred[t+off]; __syncthreads(); }
    if (t == 0) s_sums[0] = sred[0];
    __syncthreads();

    // text audit sum (32 partials)
    sred[t] = (t < 32) ? dws[16 + t] : 0.0; __syncthreads();
    for (int off = 128; off > 0; off >>= 1) { if (t < off) sred[t] += sred[t+off]; __syncthreads(); }
    if (t == 0) s_sums[1] = sred[0];
    __syncthreads();

    // sum_i |wtq_i|
    double aw = 0.0;
    if (t < 64) {
        const int d0 = 4 * t;
        aw = (double)fabsf(Wt[d0] + Wt[d0+1] + Wt[d0+2] + Wt[d0+3]);
    }
    sred[t] = aw; __syncthreads();
    for (int off = 128; off > 0; off >>= 1) { if (t < off) sred[t] += sred[t+off]; __syncthreads(); }
    if (t == 0) s_sums[2] = sred[0];
    __syncthreads();

    if (t == 0) {
        double mv = 0.0, mt = 0.0;
        for (int b = 0; b < 8; ++b) { mv += sphi[b]; mt += sphi[8 + b]; }
        mv /= 8.0; mt /= 8.0;
        const double interf = fabs(mv - mt);
        for (int b = 0; b < 8; ++b)
            out[b] = (float)exp(-fabs(sphi[16 + b] - interf));
        out[8]  = (float)interf;
        out[9]  = (float)(s_sums[0] / 2097152.0);              // 8 * 4096 * 64
        out[10] = (float)(s_sums[1] * s_sums[2] / 4194304.0);  // 8 * 8192 * 64
    }
}

extern "C" void kernel_launch(void* const* d_in, const int* in_sizes, int n_in,
                              void* d_out, int out_size, void* d_ws, size_t ws_size,
                              hipStream_t stream) {
    (void)in_sizes; (void)n_in; (void)out_size; (void)ws_size;
    const float* vis = (const float*)d_in[0];
    const float* txt = (const float*)d_in[1];
    const float* gen = (const float*)d_in[2];
    const float* Wv  = (const float*)d_in[3];
    const float* bv  = (const float*)d_in[4];
    const float* Wt  = (const float*)d_in[5];
    const float* bt  = (const float*)d_in[6];
    const float* Wg  = (const float*)d_in[7];
    const float* bg  = (const float*)d_in[8];
    int*    counter = (int*)d_ws;
    float*  wsf = (float*)((char*)d_ws + 256);
    double* dws = (double*)((char*)d_ws + 65536);
    float*  out = (float*)d_out;

    hipMemsetAsync(d_ws, 0, 64, stream);   // zero completion counter each call
    hipLaunchKernelGGL(fused_kernel, dim3(NBLK), dim3(256), 0, stream,
                       vis, txt, gen, Wv, bv, Wt, bt, Wg, bg, counter, wsf, dws, out);
}

// Round 10
// 35.846 us; speedup vs baseline: 1.2338x; 1.2338x over previous
//
#include <hip/hip_runtime.h>
#include <math.h>

// Problem constants (from setup_inputs)
#define BB 8
#define HW 4096
#define LTXT 8192
#define GG 4096
#define DD 256

// Worker grid: 1120 blocks x 128 threads, thread = one input row (64 quats)
//   [0,256)     vision chains:  b = id/32,        chunk = id%32   (128 rows each)
//   [256,768)   text chains:    b = (id-256)/64,  chunk = %64
//   [768,1024)  genomic chains: b = (id-768)/32,  chunk = %32
//   [1024,1056) vision audit (32 blocks, thread = row)
//   [1056,1120) text audit (64 blocks, thread = position)
//
// ws: floats [0,1024) vision chunk products, [1024,3072) text, [3072,4096) genomic
//     doubles @byte 65536: [0,32) vision-audit partials, [32,96) text-audit partials

struct QF { float w, x, y, z; };

__device__ __forceinline__ QF qmulf(const QF a, const QF b) {
    QF r;
    r.w = fmaf(a.w, b.w, -fmaf(a.x, b.x, fmaf(a.y, b.y, a.z * b.z)));
    r.x = fmaf(a.w, b.x, fmaf(a.x, b.w, fmaf(a.y, b.z, -(a.z * b.y))));
    r.y = fmaf(a.w, b.y, fmaf(a.y, b.w, fmaf(a.z, b.x, -(a.x * b.z))));
    r.z = fmaf(a.w, b.z, fmaf(a.x, b.y, fmaf(a.z, b.w, -(a.y * b.x))));
    return r;
}

// Ordered (non-commutative) 64-lane butterfly: lower lane's product on the left.
__device__ __forceinline__ QF wave_ordered_prod(QF p, int lane) {
    #pragma unroll
    for (int s = 1; s < 64; s <<= 1) {
        QF o;
        o.w = __shfl_xor(p.w, s, 64);
        o.x = __shfl_xor(p.x, s, 64);
        o.y = __shfl_xor(p.y, s, 64);
        o.z = __shfl_xor(p.z, s, 64);
        const bool hi = (lane & s) != 0;
        QF a = hi ? o : p;
        QF b = hi ? p : o;
        p = qmulf(a, b);
    }
    return p;
}

// Thread = one row. Software-pipelined double-buffered weight staging (R5 form).
// Deferred normalization: raw product + s = prod(n_f32 + 1e-8f), one divide/batch.
// Block = 128 threads (2 waves).
template<int K, int BQ>
__device__ __forceinline__ void chain_block(
    const float* __restrict__ X, const float* __restrict__ W,
    const float* __restrict__ bias, int rowBase,
    float* __restrict__ out4, float* sprod)
{
    constexpr int V = K + 1;
    constexpr int NB = 64 / BQ;
    const int t = threadIdx.x;
    const int r = rowBase + t;
    float xv[K];
    #pragma unroll
    for (int k = 0; k < K; ++k) xv[k] = X[(size_t)r * K + k];

    float4 A[BQ * V], Bb[BQ * V];
    QF p = {1.0f, 0.0f, 0.0f, 0.0f};

    auto LOADB = [&](float4* dst, int bidx) {
        const float* bb = bias + 4 * (bidx * BQ);
        const float* wb = W + 4 * (bidx * BQ);
        #pragma unroll
        for (int j = 0; j < BQ; ++j) {
            dst[j * V + 0] = *(const float4*)(bb + 4 * j);
            #pragma unroll
            for (int k = 0; k < K; ++k)
                dst[j * V + 1 + k] = *(const float4*)(wb + k * DD + 4 * j);
        }
    };

    auto COMPUTE = [&](const float4* src, int bidx) {
        QF pb; float sb;
        #pragma unroll
        for (int j = 0; j < BQ; ++j) {
            const float4 b4 = src[j * V + 0];
            float l0 = b4.x, l1 = b4.y, l2 = b4.z, l3 = b4.w;
            #pragma unroll
            for (int k = 0; k < K; ++k) {
                const float4 w4 = src[j * V + 1 + k];
                l0 = fmaf(xv[k], w4.x, l0);
                l1 = fmaf(xv[k], w4.y, l1);
                l2 = fmaf(xv[k], w4.z, l2);
                l3 = fmaf(xv[k], w4.w, l3);
            }
            const float n = sqrtf(fmaf(l0, l0, fmaf(l1, l1, fmaf(l2, l2, l3 * l3))));
            QF q = { l0, l1, l2, l3 };
            if (j == 0) { pb = q; sb = n + 1e-8f; }
            else        { pb = qmulf(pb, q); sb *= (n + 1e-8f); }
        }
        const float inv = 1.0f / sb;
        QF pbn = { pb.w * inv, pb.x * inv, pb.y * inv, pb.z * inv };
        if (bidx == 0) p = pbn;
        else           p = qmulf(p, pbn);
    };

    LOADB(A, 0);
    for (int gg = 0; gg < NB / 2; ++gg) {
        LOADB(Bb, 2 * gg + 1);
        COMPUTE(A, 2 * gg);
        const int nb = (2 * gg + 2 < NB) ? (2 * gg + 2) : (NB - 1);
        LOADB(A, nb);
        COMPUTE(Bb, 2 * gg + 1);
    }

    const int lane = t & 63;
    p = wave_ordered_prod(p, lane);

    const int w = t >> 6;                 // 0..1
    if (lane == 0) { sprod[w*4+0] = p.w; sprod[w*4+1] = p.x; sprod[w*4+2] = p.y; sprod[w*4+3] = p.z; }
    __syncthreads();
    if (t == 0) {
        QF pp = { sprod[0], sprod[1], sprod[2], sprod[3] };
        QF o  = { sprod[4], sprod[5], sprod[6], sprod[7] };
        pp = qmulf(pp, o);
        float4 outv = { pp.w, pp.x, pp.y, pp.z };
        *(float4*)out4 = outv;
    }
}

__global__ __launch_bounds__(128) void worker_kernel(
    const float* __restrict__ vis, const float* __restrict__ txt, const float* __restrict__ gen,
    const float* __restrict__ Wv, const float* __restrict__ bv,
    const float* __restrict__ Wt, const float* __restrict__ bt,
    const float* __restrict__ Wg, const float* __restrict__ bg,
    float* __restrict__ wsf, double* __restrict__ dws)
{
    __shared__ double sred[128];
    float* sprod = (float*)sred;

    const int t  = threadIdx.x;
    const int id = blockIdx.x;

    if (id < 256) {
        const int b = id >> 5, chunk = id & 31;
        chain_block<3, 4>(vis + (size_t)b * HW * 3, Wv, bv, chunk * 128,
                          wsf + (size_t)id * 4, sprod);
    } else if (id < 768) {
        const int i2 = id - 256;
        const int b = i2 >> 6, chunk = i2 & 63;
        chain_block<1, 8>(txt + (size_t)b * LTXT, Wt, bt, chunk * 128,
                          wsf + 1024 + (size_t)i2 * 4, sprod);
    } else if (id < 1024) {
        const int i2 = id - 768;
        const int b = i2 >> 5, chunk = i2 & 31;
        chain_block<4, 2>(gen + (size_t)b * GG * 4, Wg, bg, chunk * 128,
                          wsf + 3072 + (size_t)i2 * 4, sprod);
    } else if (id < 1056) {
        // ---------------- vision audit: thread = row ----------------
        const int aid = id - 1024;
        const int r = aid * 128 + t;          // 0..4095
        float gx[8], gy[8], gz[8];
        {
            float vx[8], vy[8], vz[8];
            #pragma unroll
            for (int b = 0; b < 8; ++b) {
                const size_t base = ((size_t)b * HW + r) * 3;
                vx[b] = vis[base]; vy[b] = vis[base+1]; vz[b] = vis[base+2];
            }
            #pragma unroll
            for (int b = 0; b < 8; ++b) {
                if (b == 0)      { gx[b] = vx[1]-vx[0];  gy[b] = vy[1]-vy[0];  gz[b] = vz[1]-vz[0]; }
                else if (b == 7) { gx[b] = vx[7]-vx[6];  gy[b] = vy[7]-vy[6];  gz[b] = vz[7]-vz[6]; }
                else             { gx[b] = (vx[b+1]-vx[b-1])*0.5f; gy[b] = (vy[b+1]-vy[b-1])*0.5f; gz[b] = (vz[b+1]-vz[b-1])*0.5f; }
            }
        }
        double acc = 0.0;
        #pragma unroll 4
        for (int i = 0; i < 64; ++i) {
            const float4 a0 = *(const float4*)(Wv + 4*i);
            const float4 a1 = *(const float4*)(Wv + DD + 4*i);
            const float4 a2 = *(const float4*)(Wv + 2*DD + 4*i);
            const float wq0 = a0.x + a0.y + a0.z + a0.w;
            const float wq1 = a1.x + a1.y + a1.z + a1.w;
            const float wq2 = a2.x + a2.y + a2.z + a2.w;
            float acc8 = 0.0f;
            #pragma unroll
            for (int b = 0; b < 8; ++b)
                acc8 += fabsf(fmaf(gx[b], wq0, fmaf(gy[b], wq1, gz[b] * wq2)));
            acc += (double)acc8;
        }
        sred[t] = acc;
        __syncthreads();
        for (int off = 64; off > 0; off >>= 1) {
            if (t < off) sred[t] += sred[t + off];
            __syncthreads();
        }
        if (t == 0) dws[aid] = sred[0];
    } else {
        // ---------------- text audit (gradient factor) ----------------
        const int aid = id - 1056;
        const int l = aid * 128 + t;          // 0..8191
        float tv[8];
        #pragma unroll
        for (int b = 0; b < 8; ++b) tv[b] = txt[(size_t)b * LTXT + l];
        double acc = 0.0;
        #pragma unroll
        for (int b = 0; b < 8; ++b) {
            float gb;
            if (b == 0)      gb = tv[1] - tv[0];
            else if (b == 7) gb = tv[7] - tv[6];
            else             gb = (tv[b+1] - tv[b-1]) * 0.5f;
            acc += (double)fabsf(gb);
        }
        sred[t] = acc;
        __syncthreads();
        for (int off = 64; off > 0; off >>= 1) {
            if (t < off) sred[t] += sred[t + off];
            __syncthreads();
        }
        if (t == 0) dws[32 + aid] = sred[0];
    }
}

__global__ __launch_bounds__(256) void finalize_kernel(
    const float* __restrict__ vis, const float* __restrict__ txt, const float* __restrict__ gen,
    const float* __restrict__ Wv, const float* __restrict__ bv,
    const float* __restrict__ Wt, const float* __restrict__ bt,
    const float* __restrict__ Wg, const float* __restrict__ bg,
    const float* __restrict__ wsf, const double* __restrict__ dws,
    float* __restrict__ out)
{
    __shared__ double sphi[24];     // phi[m][b]
    __shared__ double sred[256];
    __shared__ double s_sumv, s_sumt, s_sumw;
    const int t = threadIdx.x;
    const int lane = t & 63, w = t >> 6;

    // each wave handles 6 (m,b) pairs; lane-per-chunk ordered butterfly combine
    #pragma unroll
    for (int j = 0; j < 6; ++j) {
        const int pair = w * 6 + j;          // 0..23
        const int m = pair >> 3, b = pair & 7;
        const int nch = (m == 1) ? 64 : 32;
        const float* base = wsf + ((m == 0) ? 0 : (m == 1) ? 1024 : 3072) + (size_t)b * nch * 4;
        QF p = { 1.0f, 0.0f, 0.0f, 0.0f };
        if (lane < nch) {
            const float4 c0 = *(const float4*)(base + lane * 4);
            p = { c0.x, c0.y, c0.z, c0.w };
        }
        p = wave_ordered_prod(p, lane);
        if (lane == 0) {
            float lat[4];
            if (m == 0) {
                const float x0 = vis[(size_t)b*HW*3], x1 = vis[(size_t)b*HW*3+1], x2 = vis[(size_t)b*HW*3+2];
                #pragma unroll
                for (int c = 0; c < 4; ++c)
                    lat[c] = fmaf(x0, Wv[c], fmaf(x1, Wv[DD+c], fmaf(x2, Wv[2*DD+c], bv[c])));
            } else if (m == 1) {
                const float x0 = txt[(size_t)b*LTXT];
                #pragma unroll
                for (int c = 0; c < 4; ++c) lat[c] = fmaf(x0, Wt[c], bt[c]);
            } else {
                const float x0 = gen[(size_t)b*GG*4], x1 = gen[(size_t)b*GG*4+1],
                            x2 = gen[(size_t)b*GG*4+2], x3 = gen[(size_t)b*GG*4+3];
                #pragma unroll
                for (int c = 0; c < 4; ++c)
                    lat[c] = fmaf(x0, Wg[c], fmaf(x1, Wg[DD+c], fmaf(x2, Wg[2*DD+c], fmaf(x3, Wg[3*DD+c], bg[c]))));
            }
            const float n = sqrtf(fmaf(lat[0], lat[0], fmaf(lat[1], lat[1], fmaf(lat[2], lat[2], lat[3] * lat[3]))));
            const float inv = 1.0f / (n + 1e-8f);
            QF q0 = { lat[0]*inv, lat[1]*inv, lat[2]*inv, lat[3]*inv };
            p = qmulf(p, q0);
            double ww = (double)p.w;
            if (ww > 1.0) ww = 1.0;
            if (ww < -1.0) ww = -1.0;
            sphi[pair] = 2.0 * acos(ww);
        }
    }
    __syncthreads();

    // vision audit sum (32 partials)
    sred[t] = (t < 32) ? dws[t] : 0.0; __syncthreads();
    for (int off = 128; off > 0; off >>= 1) { if (t < off) sred[t] += sred[t+off]; __syncthreads(); }
    if (t == 0) s_sumv = sred[0];
    __syncthreads();

    // text audit sum (64 partials)
    sred[t] = (t < 64) ? dws[32 + t] : 0.0; __syncthreads();
    for (int off = 128; off > 0; off >>= 1) { if (t < off) sred[t] += sred[t+off]; __syncthreads(); }
    if (t == 0) s_sumt = sred[0];
    __syncthreads();

    // sum_i |wtq_i|
    double aw = 0.0;
    if (t < 64) {
        const int d0 = 4 * t;
        aw = (double)fabsf(Wt[d0] + Wt[d0+1] + Wt[d0+2] + Wt[d0+3]);
    }
    sred[t] = aw; __syncthreads();
    for (int off = 128; off > 0; off >>= 1) { if (t < off) sred[t] += sred[t+off]; __syncthreads(); }
    if (t == 0) s_sumw = sred[0];
    __syncthreads();

    if (t == 0) {
        double mv = 0.0, mt = 0.0;
        for (int b = 0; b < 8; ++b) { mv += sphi[b]; mt += sphi[8 + b]; }
        mv /= 8.0; mt /= 8.0;
        const double interf = fabs(mv - mt);
        for (int b = 0; b < 8; ++b)
            out[b] = (float)exp(-fabs(sphi[16 + b] - interf));
        out[8]  = (float)interf;
        out[9]  = (float)(s_sumv / 2097152.0);            // 8 * 4096 * 64
        out[10] = (float)(s_sumt * s_sumw / 4194304.0);   // 8 * 8192 * 64
    }
}

extern "C" void kernel_launch(void* const* d_in, const int* in_sizes, int n_in,
                              void* d_out, int out_size, void* d_ws, size_t ws_size,
                              hipStream_t stream) {
    (void)in_sizes; (void)n_in; (void)out_size; (void)ws_size;
    const float* vis = (const float*)d_in[0];
    const float* txt = (const float*)d_in[1];
    const float* gen = (const float*)d_in[2];
    const float* Wv  = (const float*)d_in[3];
    const float* bv  = (const float*)d_in[4];
    const float* Wt  = (const float*)d_in[5];
    const float* bt  = (const float*)d_in[6];
    const float* Wg  = (const float*)d_in[7];
    const float* bg  = (const float*)d_in[8];
    float*  wsf = (float*)d_ws;
    double* dws = (double*)((char*)d_ws + 65536);
    float*  out = (float*)d_out;

    hipLaunchKernelGGL(worker_kernel, dim3(1120), dim3(128), 0, stream,
                       vis, txt, gen, Wv, bv, Wt, bt, Wg, bg, wsf, dws);
    hipLaunchKernelGGL(finalize_kernel, dim3(1), dim3(256), 0, stream,
                       vis, txt, gen, Wv, bv, Wt, bt, Wg, bg, wsf, dws, out);
}